// Round 3
// 490.615 us; speedup vs baseline: 1.0985x; 1.0985x over previous
//
#include <hip/hip_runtime.h>

// AttentionHead: B=8, S1=S2=2048, E=P=1024. Inputs fp32, output fp32.
// Round 7 (3rd submit; rounds 1-2 died in broker acquisition, no kernel
// diagnostics; full fault-audit found no OOB/hang path — see journal):
// all GEMMs on a 256x256x64 8-phase counted-vmcnt kernel (T2 swizzle +
// T3/T4 pipeline + T5 setprio, per the m201 template). Projection inputs
// pre-converted fp32->bf16 (memory-bound pass) into a staging buffer
// aliasing the dead scores region; q/k/v run serially so one 33.5 MB
// buffer suffices. Workspace layout unchanged (167.8 MB).

typedef unsigned short u16;
typedef __bf16 bf16x8 __attribute__((ext_vector_type(8)));
typedef float f32x4 __attribute__((ext_vector_type(4)));

__device__ __forceinline__ float b2f(u16 u) {
    union { unsigned i; float f; } x; x.i = ((unsigned)u) << 16; return x.f;
}
__device__ __forceinline__ u16 f2b(float f) {
    union { float f; unsigned i; } x; x.f = f;
    unsigned r = x.i + 0x7FFFu + ((x.i >> 16) & 1u);
    return (u16)(r >> 16);
}

// fp32 -> bf16 pack (W, bias, and the q/k/v inputs)
__global__ __launch_bounds__(256)
void convert_f32_bf16(const float* __restrict__ src, u16* __restrict__ dst, long n)
{
    long i = ((long)blockIdx.x * 256 + threadIdx.x) * 8;
    if (i >= n) return;
    const float4* s = (const float4*)(src + i);
    float4 a = s[0], b = s[1];
    ushort4 lo, hi;
    lo.x = f2b(a.x); lo.y = f2b(a.y); lo.z = f2b(a.z); lo.w = f2b(a.w);
    hi.x = f2b(b.x); hi.y = f2b(b.y); hi.z = f2b(b.z); hi.w = f2b(b.w);
    *(ushort4*)(dst + i) = lo;
    *(ushort4*)(dst + i + 4) = hi;
}

// ---------------------------------------------------------------------------
// 256x256 8-phase GEMM: C = alpha*(A B^T) + bias. A:(M,K) lda=K bf16;
// B:(N,K) ldb=K bf16. 512 threads = 8 waves (2M x 4N), per-wave 128x64 out.
// BK=64, 2 K-tiles per iteration, 2-buffer 128 KiB LDS, one half-tile
// global_load_lds stage per phase, counted vmcnt(4) at phases 4/8 only.
// Stage slot map (iteration i computes tiles 2i/buf0, 2i+1/buf1):
//   P0: buf1.Ah0(2i+1)  P1: buf1.Ah1(2i+1)  P2: buf0.Bh0(2i+2)  P3: buf0.Bh1(2i+2)
//   P4: buf0.Ah0(2i+2)  P5: buf0.Ah1(2i+2)  P6: buf1.Bh0(2i+3)  P7: buf1.Bh1(2i+3)
// Land checks (2 loads/stage, vmcnt(4) leaves newest 2 stages in flight):
//   end-P3: {prevP6,prevP7,P0,P1} landed -> buf1 complete before P4.   OK
//   end-P7: {P2,P3,P4,P5} landed -> buf0 complete before next P0.      OK
// Overwrite checks: each stage targets a region whose last ds_read completed
// before a strictly earlier barrier (lgkmcnt(0) precedes each phase's MFMA,
// which precedes the trailing s_barrier).                               OK
// LDS swizzle (proven, conflicts=0): LDS(row, chunk c) holds global chunk
// (c ^ (row&7)); staged via pre-swizzled global source, linear LDS dest.
// em 0: bf16 C (+bias, alpha). em 1: fp32 C. em 2: transposed vT bf16 store.
// ---------------------------------------------------------------------------

#define BARX()   __builtin_amdgcn_s_barrier()
#define WAITL0() asm volatile("s_waitcnt lgkmcnt(0)" ::: "memory")
#define WV4()    asm volatile("s_waitcnt vmcnt(4)" ::: "memory")
#define WV0()    asm volatile("s_waitcnt vmcnt(0)" ::: "memory")
#define PRIO1()  __builtin_amdgcn_s_setprio(1)
#define PRIO0()  __builtin_amdgcn_s_setprio(0)

__global__ __launch_bounds__(512, 2)
void gemm8(const u16* __restrict__ A, const u16* __restrict__ B,
           void* __restrict__ C, const u16* __restrict__ bias,
           int K, float alpha, int em, int ldc,
           long zA, long zB, long zC, int pw, int ph)
{
    __shared__ __align__(16) u16 lds[65536];   // 128 KB: [2 buf][A|B][256][64]

    const int z = blockIdx.z;
    const u16* Ap = A + zA * z;
    const u16* Bp = B + zB * z;
    const long coff = zC * z;

    // XCD patch remap (bijective for all grids used: 256/64/32 blocks)
    int tx = blockIdx.x, ty = blockIdx.y;
    if (pw > 0) {
        const int gx = gridDim.x;
        const int lin = ty * gx + tx;
        const int xcd = lin & 7, ii = lin >> 3;
        const int pcols = gx / pw;
        const int pr = xcd / pcols, pc = xcd - pr * pcols;
        tx = pc * pw + (ii % pw);
        ty = pr * ph + (ii / pw);
    }
    const int bm0 = ty << 8, bn0 = tx << 8;

    const int tid = threadIdx.x;
    const int wave = tid >> 6, lane = tid & 63;
    const int wm = wave >> 2, wn = wave & 3;       // 2 x 4 wave grid
    const int quad = lane >> 4, l15 = lane & 15;
    const int sw = l15 & 7;

    // staging geometry: half h = 128 rows; q in {0,1}: wave covers rows
    // h*128 + q*64 + wave*8 + (lane>>3); lane chunk (lane&7). LDS dest is
    // linear (base + lane*16B); global source column pre-swizzled.
    const int srow = (wave << 3) + (lane >> 3);          // 0..63 in q-block
    const int sgc  = (((lane & 7) ^ (lane >> 3)) << 3);  // swizzled col (elems)
    const int sdst = (wave << 9) + (lane << 3);          // u16 in q-block

#define STG_A(b, h, kt) do {                                                          \
    _Pragma("unroll")                                                                 \
    for (int q_ = 0; q_ < 2; ++q_)                                                    \
        __builtin_amdgcn_global_load_lds(                                             \
            (const __attribute__((address_space(1))) void*)(                          \
                Ap + (long)(bm0 + (h)*128 + q_*64 + srow) * K + (kt) + sgc),          \
            (__attribute__((address_space(3))) void*)(                                \
                lds + (b)*32768 + ((h)*128 + q_*64)*64 + sdst),                       \
            16, 0, 0);                                                                \
} while (0)

#define STG_B(b, h, kt) do {                                                          \
    _Pragma("unroll")                                                                 \
    for (int q_ = 0; q_ < 2; ++q_)                                                    \
        __builtin_amdgcn_global_load_lds(                                             \
            (const __attribute__((address_space(1))) void*)(                          \
                Bp + (long)(bn0 + (h)*128 + q_*64 + srow) * K + (kt) + sgc),          \
            (__attribute__((address_space(3))) void*)(                                \
                lds + (b)*32768 + 16384 + ((h)*128 + q_*64)*64 + sdst),               \
            16, 0, 0);                                                                \
} while (0)

#define LDA(b, m, kk) (*(const bf16x8*)(lds + (b)*32768 +                             \
    ((wm << 7) + ((m) << 4) + l15) * 64 + (((((kk) << 2) + quad) ^ sw) << 3)))
#define LDB(b, n, kk) (*(const bf16x8*)(lds + (b)*32768 + 16384 +                     \
    ((wn << 6) + ((n) << 4) + l15) * 64 + (((((kk) << 2) + quad) ^ sw) << 3)))

#define RD_A(b, mh) do {                                                              \
    _Pragma("unroll") for (int mr = 0; mr < 4; ++mr)                                  \
    _Pragma("unroll") for (int kk = 0; kk < 2; ++kk)                                  \
        af[mr][kk] = LDA(b, (mh)*4 + mr, kk);                                         \
} while (0)
#define RD_B(b, nh) do {                                                              \
    _Pragma("unroll") for (int j = 0; j < 2; ++j)                                     \
    _Pragma("unroll") for (int kk = 0; kk < 2; ++kk)                                  \
        bq[nh][j][kk] = LDB(b, (nh)*2 + j, kk);                                       \
} while (0)

#define MMAQ(mh, nh) do {                                                             \
    _Pragma("unroll") for (int mr = 0; mr < 4; ++mr)                                  \
    _Pragma("unroll") for (int j = 0; j < 2; ++j)                                     \
    _Pragma("unroll") for (int kk = 0; kk < 2; ++kk)                                  \
        acc[(mh)*4 + mr][(nh)*2 + j] = __builtin_amdgcn_mfma_f32_16x16x32_bf16(       \
            af[mr][kk], bq[nh][j][kk], acc[(mh)*4 + mr][(nh)*2 + j], 0, 0, 0);        \
} while (0)

    f32x4 acc[8][4];
#pragma unroll
    for (int m = 0; m < 8; ++m)
#pragma unroll
        for (int n = 0; n < 4; ++n) acc[m][n] = f32x4{0.f, 0.f, 0.f, 0.f};

    bf16x8 af[4][2];        // current mh quadrant fragments
    bf16x8 bq[2][2][2];     // both nh halves, live across the 4 phases

    // prologue: tile0 -> buf0 (all 4 halves), tile1 B-halves -> buf1.
    // vmcnt(4) leaves only the 2 buf1.B stages outstanding -> buf0 landed.
    STG_B(0, 0, 0); STG_B(0, 1, 0);
    STG_A(0, 0, 0); STG_A(0, 1, 0);
    STG_B(1, 0, 64); STG_B(1, 1, 64);
    WV4(); BARX();

    const int NI = K >> 7;                 // 128 K-cols (2 tiles) per iter
    for (int i = 0; i < NI - 1; ++i) {
        const int kt0 = i << 7;
        const int kt1 = kt0 + 64, kt2 = kt0 + 128, kt3 = kt0 + 192;
        // P0
        RD_A(0, 0); RD_B(0, 0); STG_A(1, 0, kt1);
        BARX(); WAITL0(); PRIO1(); MMAQ(0, 0); PRIO0(); BARX();
        // P1
        RD_B(0, 1); STG_A(1, 1, kt1);
        BARX(); WAITL0(); PRIO1(); MMAQ(0, 1); PRIO0(); BARX();
        // P2
        RD_A(0, 1); STG_B(0, 0, kt2);
        BARX(); WAITL0(); PRIO1(); MMAQ(1, 0); PRIO0(); BARX();
        // P3 (K-tile boundary: counted wait, never 0)
        STG_B(0, 1, kt2);
        BARX(); PRIO1(); MMAQ(1, 1); PRIO0(); WV4(); BARX();
        // P4
        RD_A(1, 0); RD_B(1, 0); STG_A(0, 0, kt2);
        BARX(); WAITL0(); PRIO1(); MMAQ(0, 0); PRIO0(); BARX();
        // P5
        RD_B(1, 1); STG_A(0, 1, kt2);
        BARX(); WAITL0(); PRIO1(); MMAQ(0, 1); PRIO0(); BARX();
        // P6
        RD_A(1, 1); STG_B(1, 0, kt3);
        BARX(); WAITL0(); PRIO1(); MMAQ(1, 0); PRIO0(); BARX();
        // P7 (K-tile boundary)
        STG_B(1, 1, kt3);
        BARX(); PRIO1(); MMAQ(1, 1); PRIO0(); WV4(); BARX();
    }
    {   // final iteration: tiles 2NI-2 (buf0), 2NI-1 (buf1); only buf1.A staged
        const int kt1 = ((NI - 1) << 7) + 64;
        RD_A(0, 0); RD_B(0, 0); STG_A(1, 0, kt1);
        BARX(); WAITL0(); PRIO1(); MMAQ(0, 0); PRIO0(); BARX();
        RD_B(0, 1); STG_A(1, 1, kt1);
        BARX(); WAITL0(); PRIO1(); MMAQ(0, 1); PRIO0(); BARX();
        RD_A(0, 1);
        BARX(); WAITL0(); PRIO1(); MMAQ(1, 0); PRIO0(); BARX();
        PRIO1(); MMAQ(1, 1); PRIO0(); WV0(); BARX();   // drain: buf1.A landed
        RD_A(1, 0); RD_B(1, 0);
        BARX(); WAITL0(); PRIO1(); MMAQ(0, 0); PRIO0(); BARX();
        RD_B(1, 1);
        BARX(); WAITL0(); PRIO1(); MMAQ(0, 1); PRIO0(); BARX();
        RD_A(1, 1);
        BARX(); WAITL0(); PRIO1(); MMAQ(1, 0); PRIO0(); BARX();
        PRIO1(); MMAQ(1, 1); PRIO0();
    }

    // epilogue; C/D layout: col = lane&15, row = quad*4 + reg (m89/m91)
#pragma unroll
    for (int m = 0; m < 8; ++m) {
        const int row = bm0 + (wm << 7) + (m << 4) + (quad << 2);
#pragma unroll
        for (int n = 0; n < 4; ++n) {
            const int col = bn0 + (wn << 6) + (n << 4) + l15;
            const float bv = bias ? b2f(bias[col]) : 0.f;
            f32x4 v = acc[m][n];
            const float o0 = alpha * v[0] + bv;
            const float o1 = alpha * v[1] + bv;
            const float o2 = alpha * v[2] + bv;
            const float o3 = alpha * v[3] + bv;
            if (em == 2) {
                ushort4 pk;
                pk.x = f2b(o0); pk.y = f2b(o1); pk.z = f2b(o2); pk.w = f2b(o3);
                *(ushort4*)((u16*)C + coff + ((long)(row >> 11) << 21)
                            + ((long)col << 11) + (row & 2047)) = pk;
            } else if (em == 1) {
                float* Cf = (float*)C + coff;
                Cf[(long)(row + 0) * ldc + col] = o0;
                Cf[(long)(row + 1) * ldc + col] = o1;
                Cf[(long)(row + 2) * ldc + col] = o2;
                Cf[(long)(row + 3) * ldc + col] = o3;
            } else {
                u16* Cb = (u16*)C + coff;
                Cb[(long)(row + 0) * ldc + col] = f2b(o0);
                Cb[(long)(row + 1) * ldc + col] = f2b(o1);
                Cb[(long)(row + 2) * ldc + col] = f2b(o2);
                Cb[(long)(row + 3) * ldc + col] = f2b(o3);
            }
        }
    }
}

// in-place softmax over rows of 2048 bf16; one block (256 thr) per row
__global__ __launch_bounds__(256)
void softmax_rows(u16* __restrict__ S)
{
    const long row = blockIdx.x;
    u16* p = S + (row << 11);
    const int tid = threadIdx.x, wave = tid >> 6, lane = tid & 63;

    union { uint4 q; u16 u[8]; } d;
    d.q = ((const uint4*)p)[tid];
    float v[8];
#pragma unroll
    for (int i = 0; i < 8; i++) v[i] = b2f(d.u[i]);

    float m = v[0];
#pragma unroll
    for (int i = 1; i < 8; i++) m = fmaxf(m, v[i]);
#pragma unroll
    for (int o = 32; o; o >>= 1) m = fmaxf(m, __shfl_xor(m, o, 64));
    __shared__ float redm[4], reds[4];
    if (lane == 0) redm[wave] = m;
    __syncthreads();
    m = fmaxf(fmaxf(redm[0], redm[1]), fmaxf(redm[2], redm[3]));

    float e[8], s = 0.f;
#pragma unroll
    for (int i = 0; i < 8; i++) { e[i] = __expf(v[i] - m); s += e[i]; }
#pragma unroll
    for (int o = 32; o; o >>= 1) s += __shfl_xor(s, o, 64);
    if (lane == 0) reds[wave] = s;
    __syncthreads();
    s = reds[0] + reds[1] + reds[2] + reds[3];

    const float inv = 1.f / s;
#pragma unroll
    for (int i = 0; i < 8; i++) d.u[i] = f2b(e[i] * inv);
    ((uint4*)p)[tid] = d.q;
}

extern "C" void kernel_launch(void* const* d_in, const int* in_sizes, int n_in,
                              void* d_out, int out_size, void* d_ws, size_t ws_size,
                              hipStream_t stream) {
    const float* query = (const float*)d_in[0];   // (8,2048,1024) fp32
    const float* key   = (const float*)d_in[1];
    const float* value = (const float*)d_in[2];
    const float* W     = (const float*)d_in[3];   // (1024,1024) fp32 (P,E)
    const float* bias  = (const float*)d_in[4];   // (1024,) fp32
    float* out = (float*)d_out;                   // (8,2048,1024) fp32

    // ws (u16 elems), 167.8 MB — layout unchanged:
    //   [0, 33.5M)  sc (scores) | aliased early: xc @0 (16.7M), Wc @16.7M, bc
    //   [33.5M..)   qb | kb | vT  (3 x 16.7M)
    u16* sc  = (u16*)d_ws;
    u16* xc  = (u16*)d_ws;                 // bf16 staging for q/k/v (serial)
    u16* Wc  = (u16*)d_ws + 16777216L;
    u16* bc  = Wc + 1048576L;
    u16* qb  = (u16*)d_ws + 33554432L;
    u16* kb  = qb + 16777216L;
    u16* vT  = kb + 16777216L;

    const dim3 blk2(256), blk5(512);

    convert_f32_bf16<<<dim3(512), blk2, 0, stream>>>(W, Wc, 1048576L);
    convert_f32_bf16<<<dim3(1),   blk2, 0, stream>>>(bias, bc, 1024L);

    // projections: convert input -> xc (memory-bound), then 256^2 GEMM.
    // M=16384, N=1024, K=1024; grid 256 blocks = 1 full GPU round each.
    convert_f32_bf16<<<dim3(8192), blk2, 0, stream>>>(query, xc, 16777216L);
    gemm8<<<dim3(4, 64, 1), blk5, 0, stream>>>(xc, Wc, qb, bc,
        1024, 1.f, 0, 1024, 0, 0, 0, 4, 8);
    convert_f32_bf16<<<dim3(8192), blk2, 0, stream>>>(key, xc, 16777216L);
    gemm8<<<dim3(4, 64, 1), blk5, 0, stream>>>(xc, Wc, kb, bc,
        1024, 1.f, 0, 1024, 0, 0, 0, 4, 8);
    convert_f32_bf16<<<dim3(8192), blk2, 0, stream>>>(value, xc, 16777216L);
    gemm8<<<dim3(4, 64, 1), blk5, 0, stream>>>(xc, Wc, vT, bc,
        1024, 1.f, 2, 0, 0, 0, 0, 4, 8);

    // scores: per batch M=N=2048, K=1024, alpha=1/32
    gemm8<<<dim3(8, 8, 8), blk5, 0, stream>>>(qb, kb, sc, nullptr,
        1024, 0.03125f, 0, 2048, 2048L * 1024, 2048L * 1024, 2048L * 2048, 8, 1);

    // softmax rows (8*2048), in place
    softmax_rows<<<dim3(16384), blk2, 0, stream>>>(sc);

    // out = S @ vT^T: per batch M=2048, N=1024, K=2048, fp32 C
    gemm8<<<dim3(4, 8, 8), blk5, 0, stream>>>(sc, vT, out, nullptr,
        2048, 1.f, 1, 1024, 2048L * 2048, 1024L * 2048, 2048L * 1024, 4, 1);
}